// Round 20
// baseline (405.125 us; speedup 1.0000x reference)
//
#include <hip/hip_runtime.h>
#include <stdint.h>

#define THRESH 0.5f
#define DECAY  0.2f
#define TSTEPS 5

#define B_        32
#define CONV_ELEMS (32*256*20*20)   // 3,276,800  (NHWC: [b][y][x][ic])
#define RR        1152
#define CC        10
#define PRIM_ELEMS (32*1152*8)      // 294,912
#define DIG_ELEMS  (32*1152*160)    // 5,898,240
#define MM        256
#define NN        1152
#define KK        20736             // 81 windows * 256 ic, k' = kw*256+ic
#define KSPLIT    18
#define NCH64     18                // 64-elem K chunks per ks slice (18*64 = 1152)
#define NGG       324               // total 64-elem chunks (KK/64)

typedef __attribute__((ext_vector_type(4))) int   int32x4;
typedef __attribute__((ext_vector_type(4))) float f32x4;

// ---------------- init ----------------
__global__ void k_init_bij(float* bij) {
    int i = blockIdx.x * 256 + threadIdx.x;
    if (i < RR * CC) bij[i] = 1.0f / 1152.0f;
}

// ---------------- absmax of prim_w (once): float4 loads, 1 atomic per block ----------------
__global__ __launch_bounds__(256) void k_absmax(const float* __restrict__ w,
                                                unsigned* __restrict__ out) {
    __shared__ float sm[4];
    const f32x4* w4 = (const f32x4*)w;
    float m = 0.f;
    for (int i = blockIdx.x * 256 + threadIdx.x; i < MM * KK / 4; i += 256 * 256) {
        f32x4 v = w4[i];
        m = fmaxf(m, fmaxf(fmaxf(fabsf(v.x), fabsf(v.y)),
                           fmaxf(fabsf(v.z), fabsf(v.w))));
    }
    #pragma unroll
    for (int off = 1; off < 64; off <<= 1)
        m = fmaxf(m, __shfl_xor(m, off));
    int lane = threadIdx.x & 63, wv = threadIdx.x >> 6;
    if (lane == 0) sm[wv] = m;
    __syncthreads();
    if (threadIdx.x == 0) {
        float r = fmaxf(fmaxf(sm[0], sm[1]), fmaxf(sm[2], sm[3]));
        atomicMax(out, __float_as_uint(r));   // 256 atomics total
    }
}

// ---------------- conv1 (once): compute NCHW-style, emit NHWC via LDS transpose ----------------
__global__ __launch_bounds__(320) void k_conv1(const float* __restrict__ data,
                                               const float* __restrict__ cw,
                                               const float* __restrict__ cb,
                                               float* __restrict__ out) {
    __shared__ float sdat[784];
    __shared__ float swt[1296];
    __shared__ float sout[20 * 333];
    int b = blockIdx.x, og = blockIdx.y;
    int tid = threadIdx.x;
    for (int i = tid; i < 196; i += 320)
        ((f32x4*)sdat)[i] = ((const f32x4*)(data + b * 784))[i];
    for (int i = tid; i < 324; i += 320)
        ((f32x4*)swt)[i] = ((const f32x4*)(cw + og * 1296))[i];
    __syncthreads();
    int ocl = tid / 20, y = tid % 20;
    float acc[20];
    #pragma unroll
    for (int x = 0; x < 20; ++x) acc[x] = 0.f;
    const float* wb = &swt[ocl * 81];
    #pragma unroll
    for (int ky = 0; ky < 9; ++ky) {
        const float* dr = &sdat[(y + ky) * 28];
        float d[28];
        #pragma unroll
        for (int t4 = 0; t4 < 7; ++t4) {
            f32x4 v = ((const f32x4*)dr)[t4];
            d[t4 * 4 + 0] = v.x; d[t4 * 4 + 1] = v.y;
            d[t4 * 4 + 2] = v.z; d[t4 * 4 + 3] = v.w;
        }
        float w[9];
        #pragma unroll
        for (int q = 0; q < 9; ++q) w[q] = wb[ky * 9 + q];
        #pragma unroll
        for (int kx = 0; kx < 9; ++kx)
            #pragma unroll
            for (int x = 0; x < 20; ++x)
                acc[x] += d[x + kx] * w[kx];
    }
    float bias = cb[og * 16 + ocl];
    #pragma unroll
    for (int x = 0; x < 20; ++x)
        sout[y * 333 + x * 16 + ocl] = fmaxf(acc[x] + bias, 0.f);
    __syncthreads();
    const size_t base = (size_t)b * 102400 + og * 16;
    for (int f = tid; f < 6400; f += 320) {
        int yy = f / 320, rem = f % 320;
        out[base + (size_t)(f >> 4) * 256 + (f & 15)] = sout[yy * 333 + rem];
    }
}

// ---------------- weight quantize + FRAGMENT-LINEAR i8 digit relayout (once) ----------------
__global__ __launch_bounds__(256) void k_wsplit(const float* __restrict__ w,
                                                signed char* __restrict__ A2,
                                                const unsigned* __restrict__ mb) {
    int t = blockIdx.x * 256 + threadIdx.x;     // 16*324*64 = 331,776
    if (t >= 16 * NGG * 64) return;
    float inv = 32512.f / fmaxf(__uint_as_float(mb[0]), 1e-30f);
    int lane = t & 63;
    int rest = t >> 6;
    int gg = rest % NGG;
    int rowblk = rest / NGG;
    int row = rowblk * 16 + (lane & 15);
    int k0 = gg * 64 + (lane >> 4) * 16;
    union { signed char b[16]; int32x4 v; } H, L;
    #pragma unroll
    for (int j = 0; j < 16; ++j) {
        int k = k0 + j;
        int kw = k >> 8, ic = k & 255;
        float f = w[((size_t)row * 256 + ic) * 81 + kw];
        int q = (int)lrintf(f * inv);
        int lo = (int)(signed char)(q & 0xFF);
        int hi = (q - lo) >> 8;
        H.b[j] = (signed char)hi;
        L.b[j] = (signed char)lo;
    }
    size_t base = ((size_t)(rowblk * NGG + gg) * 2) * 1024 + lane * 16;
    *(int32x4*)(A2 + base)        = H.v;
    *(int32x4*)(A2 + base + 1024) = L.v;
}

// ---------------- convall (once): all TSTEPS conv spikes in one pass ----------------
__global__ void k_convall(const float* __restrict__ cout, unsigned char* __restrict__ spk5) {
    int i = blockIdx.x * 256 + threadIdx.x;
    if (i >= CONV_ELEMS / 4) return;
    f32x4 c = ((const f32x4*)cout)[i];
    f32x4 m = {0.f, 0.f, 0.f, 0.f};
    #pragma unroll
    for (int t = 0; t < TSTEPS; ++t) {
        unsigned pv = 0;
        #pragma unroll
        for (int j = 0; j < 4; ++j) {
            float mv = m[j];
            float ps = (mv > THRESH) ? THRESH : 0.f;
            mv = (mv - ps) * DECAY + c[j];
            m[j] = mv;
            if (mv > THRESH) pv |= (1u << (8 * j));
        }
        ((unsigned*)(spk5 + (size_t)t * CONV_ELEMS))[i] = pv;
    }
}

// ---------------- b_ij update body (age: 0=never, else steps-since-spike+1) ----------------
__device__ __forceinline__ void bij_body(int g, const uint8_t* __restrict__ age,
                                         const float* __restrict__ d2mem,
                                         float* __restrict__ bij) {
    int r = g / 160, co = g % 160, c = co / 16, o = co & 15;
    const float dtr = expf(-1.0f / 1.5f);
    float tab[5];
    tab[0] = 1.f;
    #pragma unroll
    for (int k = 1; k < 5; ++k) tab[k] = tab[k - 1] * dtr;
    float acc = 0.f;
    #pragma unroll 8
    for (int b = 0; b < B_; ++b) {
        uint8_t a = age[(size_t)b * (RR * 160) + g];
        float tv = (a == 0 || a > 5) ? 0.f : tab[a - 1];
        float d2 = (d2mem[b * 160 + co] > THRESH) ? 1.f : 0.f;
        acc += (tv - 0.1f) * d2;
    }
    #pragma unroll
    for (int off = 1; off < 16; off <<= 1) acc += __shfl_xor(acc, off);
    if (o == 0) {
        float bo = bij[r * 10 + c];
        bo = fminf(fmaxf(bo, -0.05f), 1.0f);
        bij[r * 10 + c] = bo + 0.0008f * (acc * (1.0f / 32.0f));
    }
}

// ---------------- GEMM: barrier-free, LDS-free, 64x64 tiles (grid 1296), int partials ----------------
// B fragment = 16 consecutive ic bytes per lane in NHWC spk.
// blocks 0-1295 gemm -> Cp[ks]; blocks 1296+ fused b_ij of previous step.
__global__ __launch_bounds__(256) void k_gemm(const signed char* __restrict__ A2,
                                              const unsigned char* __restrict__ spk,
                                              int* __restrict__ Cp,
                                              int do_bij,
                                              const uint8_t* __restrict__ age,
                                              const float* __restrict__ d2mem,
                                              float* __restrict__ bij) {
    int bid = blockIdx.x;
    int tid = threadIdx.x;
    if (bid >= 1296) {
        if (!do_bij) return;
        int g = (bid - 1296) * 256 + tid;        // exactly RR*160
        bij_body(g, age, d2mem, bij);
        return;
    }
    int slot = bid & 7, j = bid >> 3;            // 1296 = 8 * 162
    int tm = slot & 3, kpar = slot >> 2;         // (tm,kpar) fixed per XCD slot
    int tn = j / 9, ks2 = j % 9;                 // tn 0..17 (64-wide), ks2 0..8
    int ks = ks2 * 2 + kpar;                     // 0..17

    int wid = tid >> 6, lane = tid & 63;
    int wr = wid >> 1, wc = wid & 1;             // wave tile 32(M) x 32(N)
    int fr = lane & 15, sl = lane >> 4;

    // B per-lane row bases: n = wc*32 + jj*16 + fr
    const unsigned char* pB[2];
    #pragma unroll
    for (int jj = 0; jj < 2; ++jj) {
        int gn = tn * 64 + wc * 32 + jj * 16 + fr;
        int b = gn / 36, pos = gn % 36;
        pB[jj] = spk + ((b * 20 + (pos / 6) * 2) * 20 + (pos % 6) * 2) * 256;
    }

    // A fragment base pointers [digit][i]; chunk g = ks*NCH64 + c, stride 2048 B/chunk
    const signed char* pA[2][2];
    #pragma unroll
    for (int d = 0; d < 2; ++d)
        #pragma unroll
        for (int i = 0; i < 2; ++i) {
            int blk = tm * 4 + wr * 2 + i;
            pA[d][i] = A2 + ((size_t)((blk * NGG + ks * NCH64) * 2 + d)) * 1024 + lane * 16;
        }

    int32x4 accH[2][2] = {};
    int32x4 accL[2][2] = {};
    #pragma unroll 6
    for (int c = 0; c < NCH64; ++c) {
        int kp = ks * 1152 + c * 64 + sl * 16;   // always within one kw window
        int kw = kp >> 8, ic = kp & 255;
        int koff = ((kw / 9) * 20 + (kw % 9)) * 256 + ic;
        int32x4 bv[2];
        #pragma unroll
        for (int jj = 0; jj < 2; ++jj)
            bv[jj] = *(const int32x4*)(pB[jj] + koff);
        int32x4 av[2][2];
        #pragma unroll
        for (int d = 0; d < 2; ++d)
            #pragma unroll
            for (int i = 0; i < 2; ++i)
                av[d][i] = *(const int32x4*)(pA[d][i] + (size_t)c * 2048);
        #pragma unroll
        for (int i = 0; i < 2; ++i)
            #pragma unroll
            for (int jj = 0; jj < 2; ++jj) {
                accH[i][jj] = __builtin_amdgcn_mfma_i32_16x16x64_i8(
                    av[0][i], bv[jj], accH[i][jj], 0, 0, 0);
                accL[i][jj] = __builtin_amdgcn_mfma_i32_16x16x64_i8(
                    av[1][i], bv[jj], accL[i][jj], 0, 0, 0);
            }
    }

    // non-atomic int partial store: q = qH*256 + qL, exact in i32
    int colb = lane & 15, rb4 = (lane >> 4) * 4;
    int* Co = Cp + (size_t)ks * (MM * NN);
    #pragma unroll
    for (int i = 0; i < 2; ++i)
        #pragma unroll
        for (int jj = 0; jj < 2; ++jj) {
            int gm = tm * 64 + wr * 32 + i * 16 + rb4;
            int gn = tn * 64 + wc * 32 + jj * 16 + colb;
            #pragma unroll
            for (int q = 0; q < 4; ++q)
                Co[(size_t)(gm + q) * NN + gn] = accH[i][jj][q] * 256 + accL[i][jj][q];
        }
}

// ---------------- dig: 18-way int Cp reduce + prim membrane + u_hat + dig membrane ----------------
__global__ __launch_bounds__(320) void k_dig(const int* __restrict__ Cp,
                                             const unsigned* __restrict__ mb,
                                             const float* __restrict__ pb,
                                             float* __restrict__ pmem,
                                             const float* __restrict__ W,
                                             const float* __restrict__ bias,
                                             const float* __restrict__ bij,
                                             float* __restrict__ dmem,
                                             uint8_t* __restrict__ age,
                                             float* __restrict__ sjp) {
    __shared__ float ps[128];   // [r(4)][bl(4)][i(8)]
    int r0 = blockIdx.x * 4;
    int by = blockIdx.y;        // batch quad (0..7)
    int tid = threadIdx.x;
    if (tid < 128) {
        float s1 = fmaxf(__uint_as_float(mb[0]), 1e-30f) / 32512.f;
        int bl = tid >> 5, ff = tid & 31;       // ff: 32 consecutive f per bl
        int f = r0 * 8 + ff;
        int oc = f / 36, pos = f % 36;
        int b = by * 4 + bl;
        int n = b * 36 + pos;
        int qs = 0;
        #pragma unroll
        for (int ks = 0; ks < KSPLIT; ++ks)
            qs += Cp[(size_t)ks * (MM * NN) + (size_t)oc * NN + n];
        float sacc = pb[oc] + (float)qs * s1;
        size_t pidx = (size_t)b * 9216 + f;
        float m = pmem[pidx];
        float pso = (m > THRESH) ? THRESH : 0.f;
        m = (m - pso) * DECAY + sacc;
        pmem[pidx] = m;
        ps[(ff >> 3) * 32 + bl * 8 + (ff & 7)] = (m > THRESH) ? 1.f : 0.f;
    }
    __syncthreads();
    int co = tid % 160, bh = tid / 160;         // bh in {0,1}
    int c = co >> 4, o = co & 15;
    float bo = bias[o];

    size_t idx8[4][2];
    float  m8[4][2];
    uint8_t a8[4][2];
    #pragma unroll
    for (int r = 0; r < 4; ++r)
        #pragma unroll
        for (int bb = 0; bb < 2; ++bb) {
            int bl = bh * 2 + bb;
            idx8[r][bb] = ((size_t)((by * 4 + bl) * 1152 + r0 + r)) * 160 + co;
            m8[r][bb] = dmem[idx8[r][bb]];
            a8[r][bb] = age[idx8[r][bb]];
        }

    float sacc2[2] = {0.f, 0.f};
    #pragma unroll
    for (int r = 0; r < 4; ++r) {
        int rr = r0 + r;
        const float* wp = W + ((size_t)((rr * 10 + c) * 16 + o)) * 8;
        f32x4 w0 = *(const f32x4*)wp;
        f32x4 w1 = *(const f32x4*)(wp + 4);
        float bv = bij[rr * 10 + c];
        #pragma unroll
        for (int bb = 0; bb < 2; ++bb) {
            const float* p8 = &ps[r * 32 + (bh * 2 + bb) * 8];
            f32x4 pa = *(const f32x4*)p8;
            f32x4 pc = *(const f32x4*)(p8 + 4);
            float u = bo + w0.x * pa.x + w0.y * pa.y + w0.z * pa.z + w0.w * pa.w
                         + w1.x * pc.x + w1.y * pc.y + w1.z * pc.z + w1.w * pc.w;
            float m = m8[r][bb];
            float psv = (m > THRESH) ? THRESH : 0.f;
            m = (m - psv) * DECAY + u;
            dmem[idx8[r][bb]] = m;
            bool sp = m > THRESH;
            if (sp) sacc2[bb] += bv;
            uint8_t a = a8[r][bb];                   // 0 = never spiked
            age[idx8[r][bb]] = sp ? (uint8_t)1 : (a ? (uint8_t)(a + 1) : (uint8_t)0);
        }
    }
    size_t pbase = ((size_t)(by * 288 + blockIdx.x)) * 640;
    #pragma unroll
    for (int bb = 0; bb < 2; ++bb)
        sjp[pbase + (bh * 2 + bb) * 160 + co] = sacc2[bb];
}

// ---------------- dig2a: reduce sjp partials (k-sliced, no atomics, deterministic) ----------------
__global__ void k_dig2a(const float* __restrict__ sjp, float* __restrict__ sjp2) {
    int bx = blockIdx.x;
    int tid = threadIdx.x;
    int gx = bx % 20, ky = bx / 20;
    int e = gx * 256 + tid;               // 0..5119
    int b = e / 160, co = e % 160;
    int y = b >> 2, rem = (b & 3) * 160 + co;
    int x0 = ky * 24;
    float a = 0.f;
    #pragma unroll 8
    for (int x = x0; x < x0 + 24; ++x)
        a += sjp[((size_t)(y * 288 + x)) * 640 + rem];
    sjp2[ky * 5120 + e] = a;
}

// ---------------- dig2b: final reduce + dig2 membrane + out_mem ----------------
__global__ void k_dig2b(const float* __restrict__ sjp2, float* __restrict__ d2mem,
                        float* __restrict__ omem) {
    int e = blockIdx.x * 256 + threadIdx.x;
    if (e >= B_ * 160) return;
    float s = 0.f;
    #pragma unroll
    for (int k = 0; k < 12; ++k) s += sjp2[k * 5120 + e];
    float m = d2mem[e];
    float ps = (m > THRESH) ? THRESH : 0.f;
    d2mem[e] = (m - ps) * DECAY + s;
    omem[e] += s;
}

// ---------------- final: classes ----------------
__global__ void k_out(const float* __restrict__ omem, float* __restrict__ out) {
    int i = blockIdx.x * 64 + threadIdx.x;
    if (i >= B_ * CC) return;
    int b = i / 10, c = i % 10;
    float s = 0.f;
    #pragma unroll
    for (int o = 0; o < 16; ++o) {
        float v = omem[b * 160 + c * 16 + o] / 5.0f;
        s += v * v;
    }
    out[i] = sqrtf(s);
}

extern "C" void kernel_launch(void* const* d_in, const int* in_sizes, int n_in,
                              void* d_out, int out_size, void* d_ws, size_t ws_size,
                              hipStream_t stream) {
    const float* data   = (const float*)d_in[0];
    const float* conv_w = (const float*)d_in[1];
    const float* conv_b = (const float*)d_in[2];
    const float* prim_w = (const float*)d_in[3];
    const float* prim_b = (const float*)d_in[4];
    const float* W      = (const float*)d_in[5];
    const float* bias   = (const float*)d_in[6];
    float* out = (float*)d_out;

    char* ws = (char*)d_ws;
    size_t off = 0;
    auto alloc = [&](size_t bytes) {
        void* p = ws + off;
        off = (off + bytes + 255) & ~(size_t)255;
        return p;
    };
    // --- contiguous zero-init state block ---
    size_t zbase = off;
    float*          prim_mem = (float*)alloc((size_t)PRIM_ELEMS * 4);
    float*          dig_mem  = (float*)alloc((size_t)DIG_ELEMS * 4);
    float*          dig2_mem = (float*)alloc(5120 * 4);
    float*          out_mem  = (float*)alloc(5120 * 4);
    uint8_t*        age      = (uint8_t*)alloc(DIG_ELEMS);
    unsigned*       mb       = (unsigned*)alloc(256);
    size_t zbytes = off - zbase;
    // --- non-state scratch ---
    float*          conv_out = (float*)alloc((size_t)CONV_ELEMS * 4);
    unsigned char*  spk5     = (unsigned char*)alloc((size_t)TSTEPS * CONV_ELEMS);
    float*          sjp      = (float*)alloc((size_t)2304 * 640 * 4);
    float*          sjp2     = (float*)alloc((size_t)12 * 5120 * 4);
    float*          bij      = (float*)alloc(RR * CC * 4);
    signed char*    A2       = (signed char*)alloc((size_t)MM * KK * 2);
    int*            Cp       = (int*)alloc((size_t)KSPLIT * MM * NN * 4);

    hipMemsetAsync(ws + zbase, 0, zbytes, stream);

    k_init_bij<<<(RR * CC + 255) / 256, 256, 0, stream>>>(bij);
    k_absmax<<<256, 256, 0, stream>>>(prim_w, mb);
    k_conv1<<<dim3(32, 16), 320, 0, stream>>>(data, conv_w, conv_b, conv_out);
    k_wsplit<<<(16 * NGG * 64 + 255) / 256, 256, 0, stream>>>(prim_w, A2, mb);
    k_convall<<<(CONV_ELEMS / 4 + 255) / 256, 256, 0, stream>>>(conv_out, spk5);

    for (int t = 0; t < TSTEPS; ++t) {
        int do_bij = (t > 0);                          // b_ij(t-1); dead at t=0 and after t=4
        int ggrid = 1296 + (do_bij ? 720 : 0);
        k_gemm<<<ggrid, 256, 0, stream>>>(A2, spk5 + (size_t)t * CONV_ELEMS, Cp,
                                          do_bij, age, dig2_mem, bij);
        k_dig<<<dim3(288, 8), 320, 0, stream>>>(Cp, mb, prim_b, prim_mem, W, bias,
                                                bij, dig_mem, age, sjp);
        k_dig2a<<<240, 256, 0, stream>>>(sjp, sjp2);
        k_dig2b<<<20, 256, 0, stream>>>(sjp2, dig2_mem, out_mem);
    }
    k_out<<<(B_ * CC + 63) / 64, 64, 0, stream>>>(out_mem, out);
}

// Round 21
// 367.392 us; speedup vs baseline: 1.1027x; 1.1027x over previous
//
#include <hip/hip_runtime.h>
#include <stdint.h>

#define THRESH 0.5f
#define DECAY  0.2f
#define TSTEPS 5

#define B_        32
#define CONV_ELEMS (32*256*20*20)   // 3,276,800  (NHWC: [b][y][x][ic])
#define RR        1152
#define CC        10
#define PRIM_ELEMS (32*1152*8)      // 294,912
#define DIG_ELEMS  (32*1152*160)    // 5,898,240
#define MM        256
#define NN        1152
#define KK        20736             // 81 windows * 256 ic, k' = kw*256+ic
#define KSPLIT    18
#define NCH64     18                // 64-elem K chunks per ks slice (18*64 = 1152)
#define NGG       324               // total 64-elem chunks (KK/64)

typedef __attribute__((ext_vector_type(4))) int   int32x4;
typedef __attribute__((ext_vector_type(4))) float f32x4;

__device__ __forceinline__ void async16(void* l, const void* g) {
    __builtin_amdgcn_global_load_lds(
        (const __attribute__((address_space(1))) uint32_t*)g,
        (__attribute__((address_space(3))) uint32_t*)l, 16, 0, 0);
}

// ---------------- init ----------------
__global__ void k_init_bij(float* bij) {
    int i = blockIdx.x * 256 + threadIdx.x;
    if (i < RR * CC) bij[i] = 1.0f / 1152.0f;
}

// ---------------- absmax of prim_w (once): float4 loads, 1 atomic per block ----------------
__global__ __launch_bounds__(256) void k_absmax(const float* __restrict__ w,
                                                unsigned* __restrict__ out) {
    __shared__ float sm[4];
    const f32x4* w4 = (const f32x4*)w;
    float m = 0.f;
    for (int i = blockIdx.x * 256 + threadIdx.x; i < MM * KK / 4; i += 256 * 256) {
        f32x4 v = w4[i];
        m = fmaxf(m, fmaxf(fmaxf(fabsf(v.x), fabsf(v.y)),
                           fmaxf(fabsf(v.z), fabsf(v.w))));
    }
    #pragma unroll
    for (int off = 1; off < 64; off <<= 1)
        m = fmaxf(m, __shfl_xor(m, off));
    int lane = threadIdx.x & 63, wv = threadIdx.x >> 6;
    if (lane == 0) sm[wv] = m;
    __syncthreads();
    if (threadIdx.x == 0) {
        float r = fmaxf(fmaxf(sm[0], sm[1]), fmaxf(sm[2], sm[3]));
        atomicMax(out, __float_as_uint(r));   // 256 atomics total
    }
}

// ---------------- conv1 (once): compute NCHW-style, emit NHWC via LDS transpose ----------------
__global__ __launch_bounds__(320) void k_conv1(const float* __restrict__ data,
                                               const float* __restrict__ cw,
                                               const float* __restrict__ cb,
                                               float* __restrict__ out) {
    __shared__ float sdat[784];
    __shared__ float swt[1296];
    __shared__ float sout[20 * 333];
    int b = blockIdx.x, og = blockIdx.y;
    int tid = threadIdx.x;
    for (int i = tid; i < 196; i += 320)
        ((f32x4*)sdat)[i] = ((const f32x4*)(data + b * 784))[i];
    for (int i = tid; i < 324; i += 320)
        ((f32x4*)swt)[i] = ((const f32x4*)(cw + og * 1296))[i];
    __syncthreads();
    int ocl = tid / 20, y = tid % 20;
    float acc[20];
    #pragma unroll
    for (int x = 0; x < 20; ++x) acc[x] = 0.f;
    const float* wb = &swt[ocl * 81];
    #pragma unroll
    for (int ky = 0; ky < 9; ++ky) {
        const float* dr = &sdat[(y + ky) * 28];
        float d[28];
        #pragma unroll
        for (int t4 = 0; t4 < 7; ++t4) {
            f32x4 v = ((const f32x4*)dr)[t4];
            d[t4 * 4 + 0] = v.x; d[t4 * 4 + 1] = v.y;
            d[t4 * 4 + 2] = v.z; d[t4 * 4 + 3] = v.w;
        }
        float w[9];
        #pragma unroll
        for (int q = 0; q < 9; ++q) w[q] = wb[ky * 9 + q];
        #pragma unroll
        for (int kx = 0; kx < 9; ++kx)
            #pragma unroll
            for (int x = 0; x < 20; ++x)
                acc[x] += d[x + kx] * w[kx];
    }
    float bias = cb[og * 16 + ocl];
    #pragma unroll
    for (int x = 0; x < 20; ++x)
        sout[y * 333 + x * 16 + ocl] = fmaxf(acc[x] + bias, 0.f);
    __syncthreads();
    const size_t base = (size_t)b * 102400 + og * 16;
    for (int f = tid; f < 6400; f += 320) {
        int yy = f / 320, rem = f % 320;
        out[base + (size_t)(f >> 4) * 256 + (f & 15)] = sout[yy * 333 + rem];
    }
}

// ---------------- weight quantize + FRAGMENT-LINEAR i8 digit relayout (once) ----------------
__global__ __launch_bounds__(256) void k_wsplit(const float* __restrict__ w,
                                                signed char* __restrict__ A2,
                                                const unsigned* __restrict__ mb) {
    int t = blockIdx.x * 256 + threadIdx.x;     // 16*324*64 = 331,776
    if (t >= 16 * NGG * 64) return;
    float inv = 32512.f / fmaxf(__uint_as_float(mb[0]), 1e-30f);
    int lane = t & 63;
    int rest = t >> 6;
    int gg = rest % NGG;
    int rowblk = rest / NGG;
    int row = rowblk * 16 + (lane & 15);
    int k0 = gg * 64 + (lane >> 4) * 16;
    union { signed char b[16]; int32x4 v; } H, L;
    #pragma unroll
    for (int j = 0; j < 16; ++j) {
        int k = k0 + j;
        int kw = k >> 8, ic = k & 255;
        float f = w[((size_t)row * 256 + ic) * 81 + kw];
        int q = (int)lrintf(f * inv);
        int lo = (int)(signed char)(q & 0xFF);
        int hi = (q - lo) >> 8;
        H.b[j] = (signed char)hi;
        L.b[j] = (signed char)lo;
    }
    size_t base = ((size_t)(rowblk * NGG + gg) * 2) * 1024 + lane * 16;
    *(int32x4*)(A2 + base)        = H.v;
    *(int32x4*)(A2 + base + 1024) = L.v;
}

// ---------------- convall (once): all TSTEPS conv spikes in one pass ----------------
__global__ void k_convall(const float* __restrict__ cout, unsigned char* __restrict__ spk5) {
    int i = blockIdx.x * 256 + threadIdx.x;
    if (i >= CONV_ELEMS / 4) return;
    f32x4 c = ((const f32x4*)cout)[i];
    f32x4 m = {0.f, 0.f, 0.f, 0.f};
    #pragma unroll
    for (int t = 0; t < TSTEPS; ++t) {
        unsigned pv = 0;
        #pragma unroll
        for (int j = 0; j < 4; ++j) {
            float mv = m[j];
            float ps = (mv > THRESH) ? THRESH : 0.f;
            mv = (mv - ps) * DECAY + c[j];
            m[j] = mv;
            if (mv > THRESH) pv |= (1u << (8 * j));
        }
        ((unsigned*)(spk5 + (size_t)t * CONV_ELEMS))[i] = pv;
    }
}

// ---------------- b_ij update body (age: 0=never, else steps-since-spike+1) ----------------
__device__ __forceinline__ void bij_body(int g, const uint8_t* __restrict__ age,
                                         const float* __restrict__ d2mem,
                                         float* __restrict__ bij) {
    int r = g / 160, co = g % 160, c = co / 16, o = co & 15;
    const float dtr = expf(-1.0f / 1.5f);
    float tab[5];
    tab[0] = 1.f;
    #pragma unroll
    for (int k = 1; k < 5; ++k) tab[k] = tab[k - 1] * dtr;
    float acc = 0.f;
    #pragma unroll 8
    for (int b = 0; b < B_; ++b) {
        uint8_t a = age[(size_t)b * (RR * 160) + g];
        float tv = (a == 0 || a > 5) ? 0.f : tab[a - 1];
        float d2 = (d2mem[b * 160 + co] > THRESH) ? 1.f : 0.f;
        acc += (tv - 0.1f) * d2;
    }
    #pragma unroll
    for (int off = 1; off < 16; off <<= 1) acc += __shfl_xor(acc, off);
    if (o == 0) {
        float bo = bij[r * 10 + c];
        bo = fminf(fmaxf(bo, -0.05f), 1.0f);
        bij[r * 10 + c] = bo + 0.0008f * (acc * (1.0f / 32.0f));
    }
}

// ---------------- GEMM (blocks 0-647, int atomic C-reduce) + fused b_ij (blocks 648+) ----------------
__global__ __launch_bounds__(256) void k_gemm(const signed char* __restrict__ A2,
                                              const unsigned char* __restrict__ spk,
                                              int* __restrict__ Ci,
                                              int do_bij,
                                              const uint8_t* __restrict__ age,
                                              const float* __restrict__ d2mem,
                                              float* __restrict__ bij) {
    __shared__ signed char sB[3][128 * 64];      // [n][k64] rows 64B, slot-swizzled
    int bid = blockIdx.x;
    int tid = threadIdx.x;
    if (bid >= 648) {                            // b_ij blocks (720): only when do_bij
        if (!do_bij) return;
        int g = (bid - 648) * 256 + tid;         // exactly RR*160
        bij_body(g, age, d2mem, bij);
        return;
    }
    int slot = bid & 7, j = bid >> 3;            // 648 = 8 * 81
    int tm = slot & 3, kpar = slot >> 2;         // (tm,kpar) fixed per XCD slot
    int tn = j / 9, ks2 = j % 9;
    int ks = ks2 * 2 + kpar;                     // 0..17

    int rbB[2], slB[2];
    #pragma unroll
    for (int p = 0; p < 2; ++p) {
        int f = p * 256 + tid;
        int n = f >> 2;
        slB[p] = (f & 3) ^ (n & 3) ^ ((n >> 2) & 3);
        int gn = tn * 128 + n;
        int b = gn / 36, pos = gn % 36;
        rbB[p] = ((b * 20 + (pos / 6) * 2) * 20 + (pos % 6) * 2) * 256;
    }

    int wid = tid >> 6, lane = tid & 63;
    int wr = wid >> 1, wc = wid & 1;             // wave tile 32(M) x 64(N)
    int fr = lane & 15, sl = lane >> 4;

    const signed char* pA[2][2];
    #pragma unroll
    for (int d = 0; d < 2; ++d)
        #pragma unroll
        for (int i = 0; i < 2; ++i) {
            int blk = tm * 4 + wr * 2 + i;
            pA[d][i] = A2 + ((size_t)((blk * NGG + ks * NCH64) * 2 + d)) * 1024 + lane * 16;
        }

    int offB[4];
    #pragma unroll
    for (int jj = 0; jj < 4; ++jj) {
        int n = wc * 64 + jj * 16 + fr;
        offB[jj] = n * 64 + ((sl ^ (n & 3) ^ ((n >> 2) & 3)) << 4);
    }

#define STAGE(buf, c) do {                                                       \
        _Pragma("unroll")                                                        \
        for (int p = 0; p < 2; ++p) {                                            \
            int kp_ = ks * 1152 + (c) * 64 + slB[p] * 16;                        \
            int kw_ = kp_ >> 8, ic_ = kp_ & 255;                                 \
            async16(&sB[buf][(p * 256 + tid) * 16],                              \
                    spk + rbB[p] + ((kw_ / 9) * 20 + (kw_ % 9)) * 256 + ic_);    \
        }                                                                        \
    } while (0)

#define LOADA(dst, c) do {                                                       \
        _Pragma("unroll")                                                        \
        for (int d = 0; d < 2; ++d)                                              \
            _Pragma("unroll")                                                    \
            for (int i = 0; i < 2; ++i)                                          \
                dst[d][i] = *(const int32x4*)(pA[d][i] + (size_t)(c) * 2048);    \
    } while (0)

#define ITER(c, CUR, NXT) do {                                                   \
        asm volatile("s_waitcnt vmcnt(6)" ::: "memory");                         \
        __builtin_amdgcn_s_barrier();                                            \
        if ((c) + 2 < NCH64) STAGE(((c) + 2) % 3, (c) + 2);                      \
        if ((c) + 1 < NCH64) LOADA(NXT, (c) + 1);                                \
        int32x4 bv[4];                                                           \
        const signed char* sbc = sB[(c) % 3];                                    \
        _Pragma("unroll")                                                        \
        for (int jj = 0; jj < 4; ++jj) bv[jj] = *(const int32x4*)&sbc[offB[jj]]; \
        _Pragma("unroll")                                                        \
        for (int i = 0; i < 2; ++i)                                              \
            _Pragma("unroll")                                                    \
            for (int jj = 0; jj < 4; ++jj) {                                     \
                accH[i][jj] = __builtin_amdgcn_mfma_i32_16x16x64_i8(             \
                    CUR[0][i], bv[jj], accH[i][jj], 0, 0, 0);                    \
                accL[i][jj] = __builtin_amdgcn_mfma_i32_16x16x64_i8(             \
                    CUR[1][i], bv[jj], accL[i][jj], 0, 0, 0);                    \
            }                                                                    \
    } while (0)

    int32x4 accH[2][4] = {};
    int32x4 accL[2][4] = {};
    int32x4 aA[2][2], aB[2][2];
    STAGE(0, 0);
    STAGE(1, 1);
    LOADA(aA, 0);
    for (int c = 0; c < NCH64; c += 2) {
        ITER(c, aA, aB);
        ITER(c + 1, aB, aA);
    }
#undef ITER
#undef LOADA
#undef STAGE

    // deterministic integer split-K reduce: q = qH*256 + qL, exact in i32
    int colb = lane & 15, rb4 = (lane >> 4) * 4;
    #pragma unroll
    for (int i = 0; i < 2; ++i)
        #pragma unroll
        for (int jj = 0; jj < 4; ++jj) {
            int gm = tm * 64 + wr * 32 + i * 16 + rb4;
            int gn = tn * 128 + wc * 64 + jj * 16 + colb;
            #pragma unroll
            for (int q = 0; q < 4; ++q)
                atomicAdd(&Ci[(size_t)(gm + q) * NN + gn],
                          accH[i][jj][q] * 256 + accL[i][jj][q]);
        }
}

// ---------------- dig: Ci read + prim membrane + u_hat + dig membrane ----------------
__global__ __launch_bounds__(320) void k_dig(const int* __restrict__ Ci,
                                             const unsigned* __restrict__ mb,
                                             const float* __restrict__ pb,
                                             float* __restrict__ pmem,
                                             const float* __restrict__ W,
                                             const float* __restrict__ bias,
                                             const float* __restrict__ bij,
                                             float* __restrict__ dmem,
                                             uint8_t* __restrict__ age,
                                             float* __restrict__ sjp) {
    __shared__ float ps[128];   // [r(4)][bl(4)][i(8)]
    int r0 = blockIdx.x * 4;
    int by = blockIdx.y;        // batch quad (0..7)
    int tid = threadIdx.x;
    if (tid < 128) {
        float s1 = fmaxf(__uint_as_float(mb[0]), 1e-30f) / 32512.f;
        int bl = tid >> 5, ff = tid & 31;       // ff: 32 consecutive f per bl
        int f = r0 * 8 + ff;
        int oc = f / 36, pos = f % 36;
        int b = by * 4 + bl;
        int n = b * 36 + pos;
        float sacc = pb[oc] + (float)Ci[(size_t)oc * NN + n] * s1;
        size_t pidx = (size_t)b * 9216 + f;
        float m = pmem[pidx];
        float pso = (m > THRESH) ? THRESH : 0.f;
        m = (m - pso) * DECAY + sacc;
        pmem[pidx] = m;
        ps[(ff >> 3) * 32 + bl * 8 + (ff & 7)] = (m > THRESH) ? 1.f : 0.f;
    }
    __syncthreads();
    int co = tid % 160, bh = tid / 160;         // bh in {0,1}
    int c = co >> 4, o = co & 15;
    float bo = bias[o];

    size_t idx8[4][2];
    float  m8[4][2];
    uint8_t a8[4][2];
    #pragma unroll
    for (int r = 0; r < 4; ++r)
        #pragma unroll
        for (int bb = 0; bb < 2; ++bb) {
            int bl = bh * 2 + bb;
            idx8[r][bb] = ((size_t)((by * 4 + bl) * 1152 + r0 + r)) * 160 + co;
            m8[r][bb] = dmem[idx8[r][bb]];
            a8[r][bb] = age[idx8[r][bb]];
        }

    float sacc2[2] = {0.f, 0.f};
    #pragma unroll
    for (int r = 0; r < 4; ++r) {
        int rr = r0 + r;
        const float* wp = W + ((size_t)((rr * 10 + c) * 16 + o)) * 8;
        f32x4 w0 = *(const f32x4*)wp;
        f32x4 w1 = *(const f32x4*)(wp + 4);
        float bv = bij[rr * 10 + c];
        #pragma unroll
        for (int bb = 0; bb < 2; ++bb) {
            const float* p8 = &ps[r * 32 + (bh * 2 + bb) * 8];
            f32x4 pa = *(const f32x4*)p8;
            f32x4 pc = *(const f32x4*)(p8 + 4);
            float u = bo + w0.x * pa.x + w0.y * pa.y + w0.z * pa.z + w0.w * pa.w
                         + w1.x * pc.x + w1.y * pc.y + w1.z * pc.z + w1.w * pc.w;
            float m = m8[r][bb];
            float psv = (m > THRESH) ? THRESH : 0.f;
            m = (m - psv) * DECAY + u;
            dmem[idx8[r][bb]] = m;
            bool sp = m > THRESH;
            if (sp) sacc2[bb] += bv;
            uint8_t a = a8[r][bb];                   // 0 = never spiked
            age[idx8[r][bb]] = sp ? (uint8_t)1 : (a ? (uint8_t)(a + 1) : (uint8_t)0);
        }
    }
    size_t pbase = ((size_t)(by * 288 + blockIdx.x)) * 640;
    #pragma unroll
    for (int bb = 0; bb < 2; ++bb)
        sjp[pbase + (bh * 2 + bb) * 160 + co] = sacc2[bb];
}

// ---------------- dig2a: blocks 0-239 reduce sjp; blocks 240-527 zero Ci for next step ----------------
__global__ void k_dig2a(const float* __restrict__ sjp, float* __restrict__ sjp2,
                        int* __restrict__ Ci) {
    int bx = blockIdx.x;
    int tid = threadIdx.x;
    if (bx < 240) {
        int gx = bx % 20, ky = bx / 20;
        int e = gx * 256 + tid;               // 0..5119
        int b = e / 160, co = e % 160;
        int y = b >> 2, rem = (b & 3) * 160 + co;
        int x0 = ky * 24;
        float a = 0.f;
        #pragma unroll 8
        for (int x = x0; x < x0 + 24; ++x)
            a += sjp[((size_t)(y * 288 + x)) * 640 + rem];
        sjp2[ky * 5120 + e] = a;
    } else {
        int idx = (bx - 240) * 256 + tid;     // 288*256 = 73728 int4 = 294912 ints
        int32x4 z = {0, 0, 0, 0};
        ((int32x4*)Ci)[idx] = z;
    }
}

// ---------------- dig2b: final reduce + dig2 membrane + out_mem ----------------
__global__ void k_dig2b(const float* __restrict__ sjp2, float* __restrict__ d2mem,
                        float* __restrict__ omem) {
    int e = blockIdx.x * 256 + threadIdx.x;
    if (e >= B_ * 160) return;
    float s = 0.f;
    #pragma unroll
    for (int k = 0; k < 12; ++k) s += sjp2[k * 5120 + e];
    float m = d2mem[e];
    float ps = (m > THRESH) ? THRESH : 0.f;
    d2mem[e] = (m - ps) * DECAY + s;
    omem[e] += s;
}

// ---------------- final: classes ----------------
__global__ void k_out(const float* __restrict__ omem, float* __restrict__ out) {
    int i = blockIdx.x * 64 + threadIdx.x;
    if (i >= B_ * CC) return;
    int b = i / 10, c = i % 10;
    float s = 0.f;
    #pragma unroll
    for (int o = 0; o < 16; ++o) {
        float v = omem[b * 160 + c * 16 + o] / 5.0f;
        s += v * v;
    }
    out[i] = sqrtf(s);
}

extern "C" void kernel_launch(void* const* d_in, const int* in_sizes, int n_in,
                              void* d_out, int out_size, void* d_ws, size_t ws_size,
                              hipStream_t stream) {
    const float* data   = (const float*)d_in[0];
    const float* conv_w = (const float*)d_in[1];
    const float* conv_b = (const float*)d_in[2];
    const float* prim_w = (const float*)d_in[3];
    const float* prim_b = (const float*)d_in[4];
    const float* W      = (const float*)d_in[5];
    const float* bias   = (const float*)d_in[6];
    float* out = (float*)d_out;

    char* ws = (char*)d_ws;
    size_t off = 0;
    auto alloc = [&](size_t bytes) {
        void* p = ws + off;
        off = (off + bytes + 255) & ~(size_t)255;
        return p;
    };
    // --- contiguous zero-init state block (Ci included: zeroed for t=0) ---
    size_t zbase = off;
    float*          prim_mem = (float*)alloc((size_t)PRIM_ELEMS * 4);
    float*          dig_mem  = (float*)alloc((size_t)DIG_ELEMS * 4);
    float*          dig2_mem = (float*)alloc(5120 * 4);
    float*          out_mem  = (float*)alloc(5120 * 4);
    uint8_t*        age      = (uint8_t*)alloc(DIG_ELEMS);
    unsigned*       mb       = (unsigned*)alloc(256);
    int*            Ci       = (int*)alloc((size_t)MM * NN * 4);
    size_t zbytes = off - zbase;
    // --- non-state scratch ---
    float*          conv_out = (float*)alloc((size_t)CONV_ELEMS * 4);
    unsigned char*  spk5     = (unsigned char*)alloc((size_t)TSTEPS * CONV_ELEMS);
    float*          sjp      = (float*)alloc((size_t)2304 * 640 * 4);
    float*          sjp2     = (float*)alloc((size_t)12 * 5120 * 4);
    float*          bij      = (float*)alloc(RR * CC * 4);
    signed char*    A2       = (signed char*)alloc((size_t)MM * KK * 2);

    hipMemsetAsync(ws + zbase, 0, zbytes, stream);

    k_init_bij<<<(RR * CC + 255) / 256, 256, 0, stream>>>(bij);
    k_absmax<<<256, 256, 0, stream>>>(prim_w, mb);
    k_conv1<<<dim3(32, 16), 320, 0, stream>>>(data, conv_w, conv_b, conv_out);
    k_wsplit<<<(16 * NGG * 64 + 255) / 256, 256, 0, stream>>>(prim_w, A2, mb);
    k_convall<<<(CONV_ELEMS / 4 + 255) / 256, 256, 0, stream>>>(conv_out, spk5);

    for (int t = 0; t < TSTEPS; ++t) {
        int do_bij = (t > 0);                          // b_ij(t-1); dead at t=0 and after t=4
        int ggrid = 648 + (do_bij ? 720 : 0);
        k_gemm<<<ggrid, 256, 0, stream>>>(A2, spk5 + (size_t)t * CONV_ELEMS, Ci,
                                          do_bij, age, dig2_mem, bij);
        k_dig<<<dim3(288, 8), 320, 0, stream>>>(Ci, mb, prim_b, prim_mem, W, bias,
                                                bij, dig_mem, age, sjp);
        k_dig2a<<<528, 256, 0, stream>>>(sjp, sjp2, Ci);   // reduce + Ci re-zero
        k_dig2b<<<20, 256, 0, stream>>>(sjp2, dig2_mem, out_mem);
    }
    k_out<<<(B_ * CC + 63) / 64, 64, 0, stream>>>(out_mem, out);
}

// Round 22
// 307.412 us; speedup vs baseline: 1.3179x; 1.1951x over previous
//
#include <hip/hip_runtime.h>
#include <stdint.h>

#define THRESH 0.5f
#define DECAY  0.2f
#define TSTEPS 5

#define B_        32
#define CONV_ELEMS (32*256*20*20)   // 3,276,800  (NHWC: [b][y][x][ic])
#define RR        1152
#define CC        10
#define PRIM_ELEMS (32*1152*8)      // 294,912
#define DIG_ELEMS  (32*1152*160)    // 5,898,240
#define MM        256
#define NN        1152
#define KK        20736             // 81 windows * 256 ic, k' = kw*256+ic
#define KSPLIT    9
#define NCH64     36                // 64-elem K chunks per ks slice (36*64 = 2304)
#define NGG       324               // total 64-elem chunks (KK/64)

typedef __attribute__((ext_vector_type(4))) int   int32x4;
typedef __attribute__((ext_vector_type(4))) float f32x4;

__device__ __forceinline__ void async16(void* l, const void* g) {
    __builtin_amdgcn_global_load_lds(
        (const __attribute__((address_space(1))) uint32_t*)g,
        (__attribute__((address_space(3))) uint32_t*)l, 16, 0, 0);
}

// ---------------- init ----------------
__global__ void k_init_bij(float* bij) {
    int i = blockIdx.x * 256 + threadIdx.x;
    if (i < RR * CC) bij[i] = 1.0f / 1152.0f;
}

// ---------------- absmax of prim_w (once): float4 loads, 1 atomic per block ----------------
__global__ __launch_bounds__(256) void k_absmax(const float* __restrict__ w,
                                                unsigned* __restrict__ out) {
    __shared__ float sm[4];
    const f32x4* w4 = (const f32x4*)w;
    float m = 0.f;
    for (int i = blockIdx.x * 256 + threadIdx.x; i < MM * KK / 4; i += 256 * 256) {
        f32x4 v = w4[i];
        m = fmaxf(m, fmaxf(fmaxf(fabsf(v.x), fabsf(v.y)),
                           fmaxf(fabsf(v.z), fabsf(v.w))));
    }
    #pragma unroll
    for (int off = 1; off < 64; off <<= 1)
        m = fmaxf(m, __shfl_xor(m, off));
    int lane = threadIdx.x & 63, wv = threadIdx.x >> 6;
    if (lane == 0) sm[wv] = m;
    __syncthreads();
    if (threadIdx.x == 0) {
        float r = fmaxf(fmaxf(sm[0], sm[1]), fmaxf(sm[2], sm[3]));
        atomicMax(out, __float_as_uint(r));   // 256 atomics total
    }
}

// ---------------- conv1 (once): compute NCHW-style, emit NHWC via LDS transpose ----------------
__global__ __launch_bounds__(320) void k_conv1(const float* __restrict__ data,
                                               const float* __restrict__ cw,
                                               const float* __restrict__ cb,
                                               float* __restrict__ out) {
    __shared__ float sdat[784];
    __shared__ float swt[1296];
    __shared__ float sout[20 * 333];
    int b = blockIdx.x, og = blockIdx.y;
    int tid = threadIdx.x;
    for (int i = tid; i < 196; i += 320)
        ((f32x4*)sdat)[i] = ((const f32x4*)(data + b * 784))[i];
    for (int i = tid; i < 324; i += 320)
        ((f32x4*)swt)[i] = ((const f32x4*)(cw + og * 1296))[i];
    __syncthreads();
    int ocl = tid / 20, y = tid % 20;
    float acc[20];
    #pragma unroll
    for (int x = 0; x < 20; ++x) acc[x] = 0.f;
    const float* wb = &swt[ocl * 81];
    #pragma unroll
    for (int ky = 0; ky < 9; ++ky) {
        const float* dr = &sdat[(y + ky) * 28];
        float d[28];
        #pragma unroll
        for (int t4 = 0; t4 < 7; ++t4) {
            f32x4 v = ((const f32x4*)dr)[t4];
            d[t4 * 4 + 0] = v.x; d[t4 * 4 + 1] = v.y;
            d[t4 * 4 + 2] = v.z; d[t4 * 4 + 3] = v.w;
        }
        float w[9];
        #pragma unroll
        for (int q = 0; q < 9; ++q) w[q] = wb[ky * 9 + q];
        #pragma unroll
        for (int kx = 0; kx < 9; ++kx)
            #pragma unroll
            for (int x = 0; x < 20; ++x)
                acc[x] += d[x + kx] * w[kx];
    }
    float bias = cb[og * 16 + ocl];
    #pragma unroll
    for (int x = 0; x < 20; ++x)
        sout[y * 333 + x * 16 + ocl] = fmaxf(acc[x] + bias, 0.f);
    __syncthreads();
    const size_t base = (size_t)b * 102400 + og * 16;
    for (int f = tid; f < 6400; f += 320) {
        int yy = f / 320, rem = f % 320;
        out[base + (size_t)(f >> 4) * 256 + (f & 15)] = sout[yy * 333 + rem];
    }
}

// ---------------- weight quantize + FRAGMENT-LINEAR i8 digit relayout (once) ----------------
__global__ __launch_bounds__(256) void k_wsplit(const float* __restrict__ w,
                                                signed char* __restrict__ A2,
                                                const unsigned* __restrict__ mb) {
    int t = blockIdx.x * 256 + threadIdx.x;     // 16*324*64 = 331,776
    if (t >= 16 * NGG * 64) return;
    float inv = 32512.f / fmaxf(__uint_as_float(mb[0]), 1e-30f);
    int lane = t & 63;
    int rest = t >> 6;
    int gg = rest % NGG;
    int rowblk = rest / NGG;
    int row = rowblk * 16 + (lane & 15);
    int k0 = gg * 64 + (lane >> 4) * 16;
    union { signed char b[16]; int32x4 v; } H, L;
    #pragma unroll
    for (int j = 0; j < 16; ++j) {
        int k = k0 + j;
        int kw = k >> 8, ic = k & 255;
        float f = w[((size_t)row * 256 + ic) * 81 + kw];
        int q = (int)lrintf(f * inv);
        int lo = (int)(signed char)(q & 0xFF);
        int hi = (q - lo) >> 8;
        H.b[j] = (signed char)hi;
        L.b[j] = (signed char)lo;
    }
    size_t base = ((size_t)(rowblk * NGG + gg) * 2) * 1024 + lane * 16;
    *(int32x4*)(A2 + base)        = H.v;
    *(int32x4*)(A2 + base + 1024) = L.v;
}

// ---------------- convall (once): all TSTEPS conv spikes in one pass ----------------
__global__ void k_convall(const float* __restrict__ cout, unsigned char* __restrict__ spk5) {
    int i = blockIdx.x * 256 + threadIdx.x;
    if (i >= CONV_ELEMS / 4) return;
    f32x4 c = ((const f32x4*)cout)[i];
    f32x4 m = {0.f, 0.f, 0.f, 0.f};
    #pragma unroll
    for (int t = 0; t < TSTEPS; ++t) {
        unsigned pv = 0;
        #pragma unroll
        for (int j = 0; j < 4; ++j) {
            float mv = m[j];
            float ps = (mv > THRESH) ? THRESH : 0.f;
            mv = (mv - ps) * DECAY + c[j];
            m[j] = mv;
            if (mv > THRESH) pv |= (1u << (8 * j));
        }
        ((unsigned*)(spk5 + (size_t)t * CONV_ELEMS))[i] = pv;
    }
}

// ---------------- MEGA-GEMM: all 5 timesteps in one launch (grid 1620) ----------------
// Proven R16 inner structure: 3-buffer LDS B-staging, vmcnt(6), A-in-regs.
// bid -> (t 0..4, tm 0..3, tn 0..8, ks 0..8); Cp5[(t*9+ks)][oc][n] int partials.
__global__ __launch_bounds__(256) void k_gemm(const signed char* __restrict__ A2,
                                              const unsigned char* __restrict__ spk5,
                                              int* __restrict__ Cp5) {
    __shared__ signed char sB[3][128 * 64];      // [n][k64] rows 64B, slot-swizzled
    int bid = blockIdx.x;
    int tid = threadIdx.x;
    int t = bid / 324;
    int r = bid % 324;                           // 324 = 4 * 81
    int tm = r & 3;
    int j = r >> 2;                              // 0..80
    int tn = j / 9, ks = j % 9;
    const unsigned char* spk = spk5 + (size_t)t * CONV_ELEMS;

    int rbB[2], slB[2];
    #pragma unroll
    for (int p = 0; p < 2; ++p) {
        int f = p * 256 + tid;
        int n = f >> 2;
        slB[p] = (f & 3) ^ (n & 3) ^ ((n >> 2) & 3);
        int gn = tn * 128 + n;
        int b = gn / 36, pos = gn % 36;
        rbB[p] = ((b * 20 + (pos / 6) * 2) * 20 + (pos % 6) * 2) * 256;
    }

    int wid = tid >> 6, lane = tid & 63;
    int wr = wid >> 1, wc = wid & 1;             // wave tile 32(M) x 64(N)
    int fr = lane & 15, sl = lane >> 4;

    const signed char* pA[2][2];
    #pragma unroll
    for (int d = 0; d < 2; ++d)
        #pragma unroll
        for (int i = 0; i < 2; ++i) {
            int blk = tm * 4 + wr * 2 + i;
            pA[d][i] = A2 + ((size_t)((blk * NGG + ks * NCH64) * 2 + d)) * 1024 + lane * 16;
        }

    int offB[4];
    #pragma unroll
    for (int jj = 0; jj < 4; ++jj) {
        int n = wc * 64 + jj * 16 + fr;
        offB[jj] = n * 64 + ((sl ^ (n & 3) ^ ((n >> 2) & 3)) << 4);
    }

#define STAGE(buf, c) do {                                                       \
        _Pragma("unroll")                                                        \
        for (int p = 0; p < 2; ++p) {                                            \
            int kp_ = ks * 2304 + (c) * 64 + slB[p] * 16;                        \
            int kw_ = kp_ >> 8, ic_ = kp_ & 255;                                 \
            async16(&sB[buf][(p * 256 + tid) * 16],                              \
                    spk + rbB[p] + ((kw_ / 9) * 20 + (kw_ % 9)) * 256 + ic_);    \
        }                                                                        \
    } while (0)

#define LOADA(dst, c) do {                                                       \
        _Pragma("unroll")                                                        \
        for (int d = 0; d < 2; ++d)                                              \
            _Pragma("unroll")                                                    \
            for (int i = 0; i < 2; ++i)                                          \
                dst[d][i] = *(const int32x4*)(pA[d][i] + (size_t)(c) * 2048);    \
    } while (0)

#define ITER(c, CUR, NXT) do {                                                   \
        asm volatile("s_waitcnt vmcnt(6)" ::: "memory");                         \
        __builtin_amdgcn_s_barrier();                                            \
        if ((c) + 2 < NCH64) STAGE(((c) + 2) % 3, (c) + 2);                      \
        if ((c) + 1 < NCH64) LOADA(NXT, (c) + 1);                                \
        int32x4 bv[4];                                                           \
        const signed char* sbc = sB[(c) % 3];                                    \
        _Pragma("unroll")                                                        \
        for (int jj = 0; jj < 4; ++jj) bv[jj] = *(const int32x4*)&sbc[offB[jj]]; \
        _Pragma("unroll")                                                        \
        for (int i = 0; i < 2; ++i)                                              \
            _Pragma("unroll")                                                    \
            for (int jj = 0; jj < 4; ++jj) {                                     \
                accH[i][jj] = __builtin_amdgcn_mfma_i32_16x16x64_i8(             \
                    CUR[0][i], bv[jj], accH[i][jj], 0, 0, 0);                    \
                accL[i][jj] = __builtin_amdgcn_mfma_i32_16x16x64_i8(             \
                    CUR[1][i], bv[jj], accL[i][jj], 0, 0, 0);                    \
            }                                                                    \
    } while (0)

    int32x4 accH[2][4] = {};
    int32x4 accL[2][4] = {};
    int32x4 aA[2][2], aB[2][2];
    STAGE(0, 0);
    STAGE(1, 1);
    LOADA(aA, 0);
    for (int c = 0; c < NCH64; c += 2) {
        ITER(c, aA, aB);
        ITER(c + 1, aB, aA);
    }
#undef ITER
#undef LOADA
#undef STAGE

    // non-atomic int partial store: q = qH*256 + qL, exact in i32
    int colb = lane & 15, rb4 = (lane >> 4) * 4;
    int* Co = Cp5 + (size_t)(t * KSPLIT + ks) * (MM * NN);
    #pragma unroll
    for (int i = 0; i < 2; ++i)
        #pragma unroll
        for (int jj = 0; jj < 4; ++jj) {
            int gm = tm * 64 + wr * 32 + i * 16 + rb4;
            int gn = tn * 128 + wc * 64 + jj * 16 + colb;
            #pragma unroll
            for (int q = 0; q < 4; ++q)
                Co[(size_t)(gm + q) * NN + gn] = accH[i][jj][q] * 256 + accL[i][jj][q];
        }
}

// ---------------- mega-cred: Ci5[t] = sum_ks Cp5[t][ks] (int4, coalesced, deterministic) ----------------
__global__ __launch_bounds__(256) void k_cred(const int* __restrict__ Cp5,
                                              int* __restrict__ Ci5) {
    int i = blockIdx.x * 256 + threadIdx.x;      // int4 index, 5*73728 total
    int t = i / 73728, rem = i % 73728;
    const int32x4* src = (const int32x4*)(Cp5 + (size_t)t * KSPLIT * (MM * NN));
    int32x4 s = {0, 0, 0, 0};
    #pragma unroll
    for (int ks = 0; ks < KSPLIT; ++ks) {
        int32x4 v = src[(size_t)ks * 73728 + rem];
        s.x += v.x; s.y += v.y; s.z += v.z; s.w += v.w;
    }
    ((int32x4*)(Ci5 + (size_t)t * (MM * NN)))[rem] = s;
}

// ---------------- b_ij update (age: 0=never, else steps-since-spike+1) ----------------
__global__ void k_bij(const uint8_t* __restrict__ age, const float* __restrict__ d2mem,
                      float* __restrict__ bij) {
    int g = blockIdx.x * 256 + threadIdx.x;
    if (g >= RR * 160) return;
    int r = g / 160, co = g % 160, c = co / 16, o = co & 15;
    const float dtr = expf(-1.0f / 1.5f);
    float tab[5];
    tab[0] = 1.f;
    #pragma unroll
    for (int k = 1; k < 5; ++k) tab[k] = tab[k - 1] * dtr;
    float acc = 0.f;
    #pragma unroll 8
    for (int b = 0; b < B_; ++b) {
        uint8_t a = age[(size_t)b * (RR * 160) + g];
        float tv = (a == 0 || a > 5) ? 0.f : tab[a - 1];
        float d2 = (d2mem[b * 160 + co] > THRESH) ? 1.f : 0.f;
        acc += (tv - 0.1f) * d2;
    }
    #pragma unroll
    for (int off = 1; off < 16; off <<= 1) acc += __shfl_xor(acc, off);
    if (o == 0) {
        float bo = bij[r * 10 + c];
        bo = fminf(fmaxf(bo, -0.05f), 1.0f);
        bij[r * 10 + c] = bo + 0.0008f * (acc * (1.0f / 32.0f));
    }
}

// ---------------- dig: Ci read + prim membrane + u_hat + dig membrane ----------------
__global__ __launch_bounds__(320) void k_dig(const int* __restrict__ Ci,
                                             const unsigned* __restrict__ mb,
                                             const float* __restrict__ pb,
                                             float* __restrict__ pmem,
                                             const float* __restrict__ W,
                                             const float* __restrict__ bias,
                                             const float* __restrict__ bij,
                                             float* __restrict__ dmem,
                                             uint8_t* __restrict__ age,
                                             float* __restrict__ sjp) {
    __shared__ float ps[128];   // [r(4)][bl(4)][i(8)]
    int r0 = blockIdx.x * 4;
    int by = blockIdx.y;        // batch quad (0..7)
    int tid = threadIdx.x;
    if (tid < 128) {
        float s1 = fmaxf(__uint_as_float(mb[0]), 1e-30f) / 32512.f;
        int bl = tid >> 5, ff = tid & 31;       // ff: 32 consecutive f per bl
        int f = r0 * 8 + ff;
        int oc = f / 36, pos = f % 36;
        int b = by * 4 + bl;
        int n = b * 36 + pos;
        float sacc = pb[oc] + (float)Ci[(size_t)oc * NN + n] * s1;
        size_t pidx = (size_t)b * 9216 + f;
        float m = pmem[pidx];
        float pso = (m > THRESH) ? THRESH : 0.f;
        m = (m - pso) * DECAY + sacc;
        pmem[pidx] = m;
        ps[(ff >> 3) * 32 + bl * 8 + (ff & 7)] = (m > THRESH) ? 1.f : 0.f;
    }
    __syncthreads();
    int co = tid % 160, bh = tid / 160;         // bh in {0,1}
    int c = co >> 4, o = co & 15;
    float bo = bias[o];

    size_t idx8[4][2];
    float  m8[4][2];
    uint8_t a8[4][2];
    #pragma unroll
    for (int r = 0; r < 4; ++r)
        #pragma unroll
        for (int bb = 0; bb < 2; ++bb) {
            int bl = bh * 2 + bb;
            idx8[r][bb] = ((size_t)((by * 4 + bl) * 1152 + r0 + r)) * 160 + co;
            m8[r][bb] = dmem[idx8[r][bb]];
            a8[r][bb] = age[idx8[r][bb]];
        }

    float sacc2[2] = {0.f, 0.f};
    #pragma unroll
    for (int r = 0; r < 4; ++r) {
        int rr = r0 + r;
        const float* wp = W + ((size_t)((rr * 10 + c) * 16 + o)) * 8;
        f32x4 w0 = *(const f32x4*)wp;
        f32x4 w1 = *(const f32x4*)(wp + 4);
        float bv = bij[rr * 10 + c];
        #pragma unroll
        for (int bb = 0; bb < 2; ++bb) {
            const float* p8 = &ps[r * 32 + (bh * 2 + bb) * 8];
            f32x4 pa = *(const f32x4*)p8;
            f32x4 pc = *(const f32x4*)(p8 + 4);
            float u = bo + w0.x * pa.x + w0.y * pa.y + w0.z * pa.z + w0.w * pa.w
                         + w1.x * pc.x + w1.y * pc.y + w1.z * pc.z + w1.w * pc.w;
            float m = m8[r][bb];
            float psv = (m > THRESH) ? THRESH : 0.f;
            m = (m - psv) * DECAY + u;
            dmem[idx8[r][bb]] = m;
            bool sp = m > THRESH;
            if (sp) sacc2[bb] += bv;
            uint8_t a = a8[r][bb];                   // 0 = never spiked
            age[idx8[r][bb]] = sp ? (uint8_t)1 : (a ? (uint8_t)(a + 1) : (uint8_t)0);
        }
    }
    size_t pbase = ((size_t)(by * 288 + blockIdx.x)) * 640;
    #pragma unroll
    for (int bb = 0; bb < 2; ++bb)
        sjp[pbase + (bh * 2 + bb) * 160 + co] = sacc2[bb];
}

// ---------------- dig2a: reduce sjp partials (k-sliced, no atomics, deterministic) ----------------
__global__ void k_dig2a(const float* __restrict__ sjp, float* __restrict__ sjp2) {
    int bx = blockIdx.x;
    int tid = threadIdx.x;
    int gx = bx % 20, ky = bx / 20;
    int e = gx * 256 + tid;               // 0..5119
    int b = e / 160, co = e % 160;
    int y = b >> 2, rem = (b & 3) * 160 + co;
    int x0 = ky * 24;
    float a = 0.f;
    #pragma unroll 8
    for (int x = x0; x < x0 + 24; ++x)
        a += sjp[((size_t)(y * 288 + x)) * 640 + rem];
    sjp2[ky * 5120 + e] = a;
}

// ---------------- dig2b: final reduce + dig2 membrane + out_mem ----------------
__global__ void k_dig2b(const float* __restrict__ sjp2, float* __restrict__ d2mem,
                        float* __restrict__ omem) {
    int e = blockIdx.x * 256 + threadIdx.x;
    if (e >= B_ * 160) return;
    float s = 0.f;
    #pragma unroll
    for (int k = 0; k < 12; ++k) s += sjp2[k * 5120 + e];
    float m = d2mem[e];
    float ps = (m > THRESH) ? THRESH : 0.f;
    d2mem[e] = (m - ps) * DECAY + s;
    omem[e] += s;
}

// ---------------- final: classes ----------------
__global__ void k_out(const float* __restrict__ omem, float* __restrict__ out) {
    int i = blockIdx.x * 64 + threadIdx.x;
    if (i >= B_ * CC) return;
    int b = i / 10, c = i % 10;
    float s = 0.f;
    #pragma unroll
    for (int o = 0; o < 16; ++o) {
        float v = omem[b * 160 + c * 16 + o] / 5.0f;
        s += v * v;
    }
    out[i] = sqrtf(s);
}

extern "C" void kernel_launch(void* const* d_in, const int* in_sizes, int n_in,
                              void* d_out, int out_size, void* d_ws, size_t ws_size,
                              hipStream_t stream) {
    const float* data   = (const float*)d_in[0];
    const float* conv_w = (const float*)d_in[1];
    const float* conv_b = (const float*)d_in[2];
    const float* prim_w = (const float*)d_in[3];
    const float* prim_b = (const float*)d_in[4];
    const float* W      = (const float*)d_in[5];
    const float* bias   = (const float*)d_in[6];
    float* out = (float*)d_out;

    char* ws = (char*)d_ws;
    size_t off = 0;
    auto alloc = [&](size_t bytes) {
        void* p = ws + off;
        off = (off + bytes + 255) & ~(size_t)255;
        return p;
    };
    // --- contiguous zero-init state block ---
    size_t zbase = off;
    float*          prim_mem = (float*)alloc((size_t)PRIM_ELEMS * 4);
    float*          dig_mem  = (float*)alloc((size_t)DIG_ELEMS * 4);
    float*          dig2_mem = (float*)alloc(5120 * 4);
    float*          out_mem  = (float*)alloc(5120 * 4);
    uint8_t*        age      = (uint8_t*)alloc(DIG_ELEMS);
    unsigned*       mb       = (unsigned*)alloc(256);
    size_t zbytes = off - zbase;
    // --- non-state scratch ---
    float*          conv_out = (float*)alloc((size_t)CONV_ELEMS * 4);
    unsigned char*  spk5     = (unsigned char*)alloc((size_t)TSTEPS * CONV_ELEMS);
    float*          sjp      = (float*)alloc((size_t)2304 * 640 * 4);
    float*          sjp2     = (float*)alloc((size_t)12 * 5120 * 4);
    float*          bij      = (float*)alloc(RR * CC * 4);
    signed char*    A2       = (signed char*)alloc((size_t)MM * KK * 2);
    int*            Cp5      = (int*)alloc((size_t)TSTEPS * KSPLIT * MM * NN * 4);
    int*            Ci5      = (int*)alloc((size_t)TSTEPS * MM * NN * 4);

    hipMemsetAsync(ws + zbase, 0, zbytes, stream);

    k_init_bij<<<(RR * CC + 255) / 256, 256, 0, stream>>>(bij);
    k_absmax<<<256, 256, 0, stream>>>(prim_w, mb);
    k_conv1<<<dim3(32, 16), 320, 0, stream>>>(data, conv_w, conv_b, conv_out);
    k_wsplit<<<(16 * NGG * 64 + 255) / 256, 256, 0, stream>>>(prim_w, A2, mb);
    k_convall<<<(CONV_ELEMS / 4 + 255) / 256, 256, 0, stream>>>(conv_out, spk5);

    // all 5 timestep GEMMs in one launch, then one reduce
    k_gemm<<<TSTEPS * 324, 256, 0, stream>>>(A2, spk5, Cp5);
    k_cred<<<TSTEPS * 288, 256, 0, stream>>>(Cp5, Ci5);

    for (int t = 0; t < TSTEPS; ++t) {
        k_dig<<<dim3(288, 8), 320, 0, stream>>>(Ci5 + (size_t)t * (MM * NN), mb,
                                                prim_b, prim_mem, W, bias,
                                                bij, dig_mem, age, sjp);
        k_dig2a<<<240, 256, 0, stream>>>(sjp, sjp2);
        k_dig2b<<<20, 256, 0, stream>>>(sjp2, dig2_mem, out_mem);
        if (t < TSTEPS - 1)
            k_bij<<<720, 256, 0, stream>>>(age, dig2_mem, bij);
    }
    k_out<<<(B_ * CC + 63) / 64, 64, 0, stream>>>(out_mem, out);
}